// Round 9
// baseline (7465.897 us; speedup 1.0000x reference)
//
#include <hip/hip_runtime.h>

// FPS: x (B=64, N=65536, 3) f32 -> out (B, M=2048, 3) f32 gathered points.
// Verified fp semantics (round 3, absmax=0):
//   d = fma(dz,dz, round(dx*dx) + round(dy*dy)), min via fminf,
//   argmax tie-break = smallest global index.
// Round-9: single-level reduce. Every wave leader publishes its wave-winner
// (4 seq-stamped u64 words: val|~idx|seq, x|seq, y|seq, z|seq) directly to
// the global ring (64 entries/batch). Wave0 of each block: one merged
// 64-lane poll over word0s -> one 6-round u64 butterfly -> stamped coord
// fetch of winner entry -> LDS broadcast. ONE __syncthreads per iteration.
// Ring safety: publish@s+2 requires barrier@s+1 <- wave0 saw all entries@s+1
// <- all blocks passed barrier@s <- their wave0 finished all parity-(s)
// reads. Per-word stamps handle store-order races.

#define FPS_B 64
#define FPS_N 65536
#define FPS_M 2048
#define FPS_T 1024
#define FPS_Q 4                    // blocks per batch
#define FPS_GT (FPS_T * FPS_Q)     // 4096 threads per batch
#define FPS_PPT (FPS_N / FPS_GT)   // 16 points per thread
#define FPS_WAVES (FPS_T / 64)     // 16 waves per block

#define ENT_U64 4                          // words per entry
#define PAR_U64 (FPS_Q * FPS_WAVES * ENT_U64)   // 256 u64 per parity
#define BATCH_U64 (2 * PAR_U64)            // 512 u64 = 4KB per batch

#define AG_LOAD(p)    __hip_atomic_load((p), __ATOMIC_RELAXED, __HIP_MEMORY_SCOPE_AGENT)
#define AG_STORE(p,v) __hip_atomic_store((p), (v), __ATOMIC_RELAXED, __HIP_MEMORY_SCOPE_AGENT)

// AGPR pin: allocation-only empty asm keeps coords resident in the unified
// register file across the loop (remat-by-reload illegal).
#define PIN4(a,b,c,d) asm volatile("" : "+a"(a), "+a"(b), "+a"(c), "+a"(d))

__global__ __launch_bounds__(FPS_T, 4)
void fps_kernel(const float* __restrict__ x, float* __restrict__ out,
                unsigned long long* __restrict__ cand) {
    const int bid = blockIdx.x;
    // XCD-affine swizzle: batch b's 4 blocks share bid%8 (same XCD under
    // round-robin dispatch). Bijective over [0,256).
    const int c = bid & 7;
    const int v = bid >> 3;
    const int q = v & 3;           // block-in-batch
    const int b = (v >> 2) * 8 + c;

    const float* xb = x + (size_t)b * FPS_N * 3;
    float* ob = out + (size_t)b * FPS_M * 3;
    unsigned long long* cb = cand + (size_t)b * BATCH_U64;

    __shared__ float s_bc[3];

    const int t = threadIdx.x;
    const int wave = t >> 6;
    const int lane = t & 63;
    const int g = q * FPS_T + t;   // 0..4095 within batch
    const int e = q * FPS_WAVES + wave;   // global entry id, 0..63

    // one-time coordinate load; point i = k*4096 + g (ascending in k)
    float cx0,cx1,cx2,cx3,cx4,cx5,cx6,cx7,cx8,cx9,cx10,cx11,cx12,cx13,cx14,cx15;
    float cy0,cy1,cy2,cy3,cy4,cy5,cy6,cy7,cy8,cy9,cy10,cy11,cy12,cy13,cy14,cy15;
    float cz0,cz1,cz2,cz3,cz4,cz5,cz6,cz7,cz8,cz9,cz10,cz11,cz12,cz13,cz14,cz15;
    float mind[FPS_PPT];
#define LOADK(k) do { const int i = (k) * FPS_GT + g; \
        cx##k = xb[3*i+0]; cy##k = xb[3*i+1]; cz##k = xb[3*i+2]; \
        mind[k] = INFINITY; } while (0)
    LOADK(0); LOADK(1); LOADK(2); LOADK(3); LOADK(4); LOADK(5); LOADK(6); LOADK(7);
    LOADK(8); LOADK(9); LOADK(10); LOADK(11); LOADK(12); LOADK(13); LOADK(14); LOADK(15);
#undef LOADK

    float px = xb[0], py = xb[1], pz = xb[2];
    if (q == 0 && t == 0) { ob[0] = px; ob[1] = py; ob[2] = pz; }

    long long budget = 1LL << 22;  // fail-safe: degrade, don't hang

    for (int s = 1; s < FPS_M; ++s) {
        // keep the 48 coord values resident across iterations
        PIN4(cx0,cx1,cx2,cx3);   PIN4(cx4,cx5,cx6,cx7);
        PIN4(cx8,cx9,cx10,cx11); PIN4(cx12,cx13,cx14,cx15);
        PIN4(cy0,cy1,cy2,cy3);   PIN4(cy4,cy5,cy6,cy7);
        PIN4(cy8,cy9,cy10,cy11); PIN4(cy12,cy13,cy14,cy15);
        PIN4(cz0,cz1,cz2,cz3);   PIN4(cz4,cz5,cz6,cz7);
        PIN4(cz8,cz9,cz10,cz11); PIN4(cz12,cz13,cz14,cz15);

        float best = -INFINITY;
        int besti = 0;
        float bx = 0.f, by = 0.f, bz = 0.f;
#define STEPK(k) do { \
        const float dx = __fsub_rn(cx##k, px); \
        const float dy = __fsub_rn(cy##k, py); \
        const float dz = __fsub_rn(cz##k, pz); \
        const float sxy = __fadd_rn(__fmul_rn(dx, dx), __fmul_rn(dy, dy)); \
        const float d = __builtin_fmaf(dz, dz, sxy); \
        const float md = fminf(mind[k], d); \
        mind[k] = md; \
        if (md > best) { best = md; besti = (k) * FPS_GT + g; \
                         bx = cx##k; by = cy##k; bz = cz##k; } } while (0)
        STEPK(0); STEPK(1); STEPK(2); STEPK(3); STEPK(4); STEPK(5); STEPK(6); STEPK(7);
        STEPK(8); STEPK(9); STEPK(10); STEPK(11); STEPK(12); STEPK(13); STEPK(14); STEPK(15);
#undef STEPK

        const unsigned long long want = (unsigned long long)s;
        const int ring = s & 1;
        unsigned long long* par = cb + ring * PAR_U64;

        // pack (val | ~idx | seq): u64 max == argmax with smallest-index
        // tie-break (val f32 >= 0 is bit-monotone; seq equal across entries)
        unsigned long long pk =
            ((unsigned long long)__float_as_uint(best) << 32) |
            ((unsigned long long)((~(unsigned)besti) & 0xFFFFu) << 11) | want;
        // wave butterfly on the packed word (6 rounds, 1 u64 cmp each)
#pragma unroll
        for (int m = 1; m <= 32; m <<= 1) {
            const unsigned long long o = __shfl_xor(pk, m);
            if (o > pk) pk = o;
        }
        // winner lane owns the winning coords (i = k*4096 + g => lane = i&63)
        const int widx0 = (int)((~(unsigned)(pk >> 11)) & 0xFFFFu);
        const int wl = widx0 & 63;
        const float wx = __shfl(bx, wl);
        const float wy = __shfl(by, wl);
        const float wz = __shfl(bz, wl);

        // wave leader publishes its wave-winner entry (lanes 0-3, one instr)
        if (lane < 4) {
            unsigned long long w;
            if (lane == 0)      w = pk;
            else if (lane == 1) w = ((unsigned long long)__float_as_uint(wx) << 32) | want;
            else if (lane == 2) w = ((unsigned long long)__float_as_uint(wy) << 32) | want;
            else                w = ((unsigned long long)__float_as_uint(wz) << 32) | want;
            AG_STORE(&par[e * ENT_U64 + lane], w);
        }

        float npx, npy, npz;
        if (wave == 0) {
            // merged poll: lane L watches word0 of entry L (all 64 entries)
            unsigned long long pv = 0;
            bool ok = false;
            for (;;) {
                if (!ok) {
                    pv = AG_LOAD(&par[lane * ENT_U64]);
                    ok = ((pv & 0x7FFull) == want);
                }
                if (__all(ok) || --budget <= 0) break;
            }
            // single 6-round butterfly over all 64 entries
#pragma unroll
            for (int m = 1; m <= 32; m <<= 1) {
                const unsigned long long o = __shfl_xor(pv, m);
                if (o > pv) pv = o;
            }
            const int widx = (int)((~(unsigned)(pv >> 11)) & 0xFFFFu);
            // entry of winner: g=idx&4095, q_win=g>>10, wave_win=(g&1023)>>6
            const int we = ((widx & 4095) >> 10) * FPS_WAVES + ((widx & 1023) >> 6);
            // stamped coord fetch (lanes 1-3, one instr per round)
            unsigned long long cw = 0;
            if (lane >= 1 && lane <= 3) {
                do { cw = AG_LOAD(&par[we * ENT_U64 + lane]); }
                while ((cw & 0x7FFull) != want && --budget > 0);
                s_bc[lane - 1] = __uint_as_float((unsigned)(cw >> 32));
            }
            npx = __uint_as_float((unsigned)(__shfl(cw, 1) >> 32));
            npy = __uint_as_float((unsigned)(__shfl(cw, 2) >> 32));
            npz = __uint_as_float((unsigned)(__shfl(cw, 3) >> 32));
            if (q == 0 && lane == 0) {
                ob[3 * s + 0] = npx; ob[3 * s + 1] = npy; ob[3 * s + 2] = npz;
            }
        }
        __syncthreads();           // the single barrier per iteration
        if (wave != 0) { npx = s_bc[0]; npy = s_bc[1]; npz = s_bc[2]; }
        px = npx; py = npy; pz = npz;
    }
}

extern "C" void kernel_launch(void* const* d_in, const int* in_sizes, int n_in,
                              void* d_out, int out_size, void* d_ws, size_t ws_size,
                              hipStream_t stream) {
    const float* x = (const float*)d_in[0];
    float* out = (float*)d_out;
    unsigned long long* cand = (unsigned long long*)d_ws;
    (void)in_sizes; (void)n_in; (void)out_size; (void)ws_size;
    // zero sync workspace each launch (stale stamps can't match: seq >= 1)
    hipMemsetAsync(d_ws, 0, FPS_B * BATCH_U64 * sizeof(unsigned long long), stream);
    fps_kernel<<<FPS_B * FPS_Q, FPS_T, 0, stream>>>(x, out, cand);
}

// Round 10
// 7290.216 us; speedup vs baseline: 1.0241x; 1.0241x over previous
//
#include <hip/hip_runtime.h>

// FPS: x (B=64, N=65536, 3) f32 -> out (B, M=2048, 3) f32 gathered points.
// Verified fp semantics (round 3, absmax=0):
//   d = fma(dz,dz, round(dx*dx) + round(dy*dy)), min via fminf,
//   argmax tie-break = smallest global index.
// Round-10 = round-8 (best, 7.33ms) + ONE change: 96KiB LDS pad forces
// exactly 1 block/CU (two 1024-thr blocks at 56 VGPR could co-schedule on
// one CU, running 2x slower and dragging the whole lockstep batch; also
// explains 38-50ms outlier replays). Protocol byte-identical to r8.

#define FPS_B 64
#define FPS_N 65536
#define FPS_M 2048
#define FPS_T 1024
#define FPS_Q 4                    // blocks per batch
#define FPS_GT (FPS_T * FPS_Q)     // 4096 threads per batch
#define FPS_PPT (FPS_N / FPS_GT)   // 16 points per thread
#define FPS_WAVES (FPS_T / 64)     // 16 waves per block

#define SLOT_U64 8                 // 64B global slot
#define BATCH_U64 (FPS_Q * 2 * SLOT_U64)

#define AG_LOAD(p)    __hip_atomic_load((p), __ATOMIC_RELAXED, __HIP_MEMORY_SCOPE_AGENT)
#define AG_STORE(p,v) __hip_atomic_store((p), (v), __ATOMIC_RELAXED, __HIP_MEMORY_SCOPE_AGENT)

// AGPR pin: allocation-only empty asm; keeps coords in the unified file.
#define PIN4(a,b,c,d) asm volatile("" : "+a"(a), "+a"(b), "+a"(c), "+a"(d))

__global__ __launch_bounds__(FPS_T, 4)
void fps_kernel(const float* __restrict__ x, float* __restrict__ out,
                unsigned long long* __restrict__ cand) {
    const int bid = blockIdx.x;
    // XCD-affine swizzle: batch b's 4 blocks share bid%8 (same XCD under
    // round-robin dispatch). Bijective over [0,256).
    const int c = bid & 7;
    const int v = bid >> 3;
    const int q = v & 3;           // block-in-batch
    const int b = (v >> 2) * 8 + c;

    const float* xb = x + (size_t)b * FPS_N * 3;
    float* ob = out + (size_t)b * FPS_M * 3;
    unsigned long long* cb = cand + (size_t)b * BATCH_U64;

    // occupancy fence: >1/2 of 160KiB LDS => hardware cannot place a second
    // block on this CU. Touched once so it isn't eliminated.
    __shared__ char s_pad[96 * 1024];
    __shared__ unsigned long long s_entry[FPS_WAVES * 4];  // 16 waves x 4 words
    __shared__ float s_bc[3];

    const int t = threadIdx.x;
    const int wave = t >> 6;
    const int lane = t & 63;
    const int g = q * FPS_T + t;   // 0..4095 within batch

    ((volatile char*)s_pad)[t * 96] = 0;   // keep the pad live (one store)

    // one-time coordinate load; point i = k*4096 + g (ascending in k)
    float cx0,cx1,cx2,cx3,cx4,cx5,cx6,cx7,cx8,cx9,cx10,cx11,cx12,cx13,cx14,cx15;
    float cy0,cy1,cy2,cy3,cy4,cy5,cy6,cy7,cy8,cy9,cy10,cy11,cy12,cy13,cy14,cy15;
    float cz0,cz1,cz2,cz3,cz4,cz5,cz6,cz7,cz8,cz9,cz10,cz11,cz12,cz13,cz14,cz15;
    float mind[FPS_PPT];
#define LOADK(k) do { const int i = (k) * FPS_GT + g; \
        cx##k = xb[3*i+0]; cy##k = xb[3*i+1]; cz##k = xb[3*i+2]; \
        mind[k] = INFINITY; } while (0)
    LOADK(0); LOADK(1); LOADK(2); LOADK(3); LOADK(4); LOADK(5); LOADK(6); LOADK(7);
    LOADK(8); LOADK(9); LOADK(10); LOADK(11); LOADK(12); LOADK(13); LOADK(14); LOADK(15);
#undef LOADK

    float px = xb[0], py = xb[1], pz = xb[2];
    if (q == 0 && t == 0) { ob[0] = px; ob[1] = py; ob[2] = pz; }

    long long budget = 1LL << 22;  // fail-safe for the global poll only

    for (int s = 1; s < FPS_M; ++s) {
        // keep the 48 coord values resident across iterations
        PIN4(cx0,cx1,cx2,cx3);   PIN4(cx4,cx5,cx6,cx7);
        PIN4(cx8,cx9,cx10,cx11); PIN4(cx12,cx13,cx14,cx15);
        PIN4(cy0,cy1,cy2,cy3);   PIN4(cy4,cy5,cy6,cy7);
        PIN4(cy8,cy9,cy10,cy11); PIN4(cy12,cy13,cy14,cy15);
        PIN4(cz0,cz1,cz2,cz3);   PIN4(cz4,cz5,cz6,cz7);
        PIN4(cz8,cz9,cz10,cz11); PIN4(cz12,cz13,cz14,cz15);

        float best = -INFINITY;
        int besti = 0;
        float bx = 0.f, by = 0.f, bz = 0.f;
#define STEPK(k) do { \
        const float dx = __fsub_rn(cx##k, px); \
        const float dy = __fsub_rn(cy##k, py); \
        const float dz = __fsub_rn(cz##k, pz); \
        const float sxy = __fadd_rn(__fmul_rn(dx, dx), __fmul_rn(dy, dy)); \
        const float d = __builtin_fmaf(dz, dz, sxy); \
        const float md = fminf(mind[k], d); \
        mind[k] = md; \
        if (md > best) { best = md; besti = (k) * FPS_GT + g; \
                         bx = cx##k; by = cy##k; bz = cz##k; } } while (0)
        STEPK(0); STEPK(1); STEPK(2); STEPK(3); STEPK(4); STEPK(5); STEPK(6); STEPK(7);
        STEPK(8); STEPK(9); STEPK(10); STEPK(11); STEPK(12); STEPK(13); STEPK(14); STEPK(15);
#undef STEPK

        // wave argmax on (val, idx), smallest-index tie-break
#pragma unroll
        for (int m = 32; m >= 1; m >>= 1) {
            const float ov = __shfl_xor(best, m);
            const int   oi = __shfl_xor(besti, m);
            if (ov > best || (ov == best && oi < besti)) { best = ov; besti = oi; }
        }
        // winner lane = besti & 63 (i = k*4096 + q*1024 + t; 4096,1024 ≡ 0 mod 64)
        const int wl = besti & 63;
        const float wx = __shfl(bx, wl);
        const float wy = __shfl(by, wl);
        const float wz = __shfl(bz, wl);

        // wave leaders deposit 4 plain words (low 11 bits left zero for seq)
        if (lane < 4) {
            unsigned long long w;
            if (lane == 0)
                w = ((unsigned long long)__float_as_uint(best) << 32) |
                    ((unsigned long long)((~(unsigned)besti) & 0xFFFFu) << 11);
            else if (lane == 1) w = ((unsigned long long)__float_as_uint(wx) << 32);
            else if (lane == 2) w = ((unsigned long long)__float_as_uint(wy) << 32);
            else                w = ((unsigned long long)__float_as_uint(wz) << 32);
            s_entry[wave * 4 + lane] = w;
        }
        __syncthreads();           // barrier 1: entries visible

        const unsigned long long want = (unsigned long long)s;
        const int ring = s & 1;
        float npx, npy, npz;

        if (wave == 0) {
            // single conflict-free load: lane L holds word (L&3) of wave (L>>2)
            unsigned long long ew = s_entry[lane];
            // butterfly max over the (lane&3)-coset; word-0 coset = block argmax
            unsigned long long u = ((lane & 3) == 0) ? ew : 0ull;
#pragma unroll
            for (int m = 4; m <= 32; m <<= 1) {
                const unsigned long long o = __shfl_xor(u, m);
                if (o > u) u = o;
            }
            const unsigned long long bw = __shfl(u, 0);   // block winner word0
            const int widx = (int)((~(unsigned)(bw >> 11)) & 0xFFFFu);
            const int wv = (widx & 1023) >> 6;            // winner wave in block
            // publish: lanes 0-3 send word0 / x / y / z, seq-stamped
            if (lane < 4) {
                const unsigned long long pw =
                    ((lane == 0) ? bw : s_entry[wv * 4 + lane]) | want;
                AG_STORE(&cb[(q * 2 + ring) * SLOT_U64 + lane], pw);
            }
            // merged poll: lane -> word (lane&15)&3 of slot (lane&15)>>2
            const int gl = lane & 15;
            unsigned long long pv = 0;
            bool ok = false;
            do {
                if (!ok) {
                    pv = AG_LOAD(&cb[((gl >> 2) * 2 + ring) * SLOT_U64 + (gl & 3)]);
                    ok = ((pv & 0x7FFull) == want);
                }
            } while (!__all(ok) && --budget > 0);
            // winner among 4 slots (word0s live in lanes 0,4,8,12)
            const unsigned long long m0 = __shfl(pv, 0);
            const unsigned long long m1 = __shfl(pv, 4);
            const unsigned long long m2 = __shfl(pv, 8);
            const unsigned long long m3 = __shfl(pv, 12);
            const unsigned long long w01 = m0 > m1 ? m0 : m1;
            const unsigned long long w23 = m2 > m3 ? m2 : m3;
            const unsigned long long w = w01 > w23 ? w01 : w23;
            const int wb = (w == m0) ? 0 : ((w == m1) ? 1 : ((w == m2) ? 2 : 3));
            npx = __uint_as_float((unsigned)(__shfl(pv, wb * 4 + 1) >> 32));
            npy = __uint_as_float((unsigned)(__shfl(pv, wb * 4 + 2) >> 32));
            npz = __uint_as_float((unsigned)(__shfl(pv, wb * 4 + 3) >> 32));
            if (lane == 0) { s_bc[0] = npx; s_bc[1] = npy; s_bc[2] = npz; }
            if (q == 0 && lane == 0) {
                ob[3 * s + 0] = npx; ob[3 * s + 1] = npy; ob[3 * s + 2] = npz;
            }
        }
        __syncthreads();           // barrier 2: broadcast visible
        if (wave != 0) { npx = s_bc[0]; npy = s_bc[1]; npz = s_bc[2]; }
        px = npx; py = npy; pz = npz;
    }
}

extern "C" void kernel_launch(void* const* d_in, const int* in_sizes, int n_in,
                              void* d_out, int out_size, void* d_ws, size_t ws_size,
                              hipStream_t stream) {
    const float* x = (const float*)d_in[0];
    float* out = (float*)d_out;
    unsigned long long* cand = (unsigned long long*)d_ws;
    (void)in_sizes; (void)n_in; (void)out_size; (void)ws_size;
    // zero sync workspace each launch (stale stamps can't match: seq >= 1)
    hipMemsetAsync(d_ws, 0, FPS_B * BATCH_U64 * sizeof(unsigned long long), stream);
    fps_kernel<<<FPS_B * FPS_Q, FPS_T, 0, stream>>>(x, out, cand);
}

// Round 11
// 7062.833 us; speedup vs baseline: 1.0571x; 1.0322x over previous
//
#include <hip/hip_runtime.h>

// FPS: x (B=64, N=65536, 3) f32 -> out (B, M=2048, 3) f32 gathered points.
// Verified fp semantics (round 3, absmax=0):
//   d = fma(dz,dz, round(dx*dx) + round(dy*dy)), min via fminf,
//   argmax tie-break = smallest global index.
// Round-11 = round-10 exchange (byte-identical) + compute-lean bundle:
//  - packed FP32 (v_pk_add/mul/fma_f32): 2 points per instruction, IEEE-RN
//    per half == bitwise-identical to scalar. Subtract done as add of
//    negated p (exact), so no asm modifiers needed.
//  - per-point argmax tracks only (val, k); winner coords recovered once
//    per wave via uniform switch (scalar pipe) + 3 shuffles.
//  - coords in VGPR pairs (pk asm forces "v"), "+v" pins block remat.

#define FPS_B 64
#define FPS_N 65536
#define FPS_M 2048
#define FPS_T 1024
#define FPS_Q 4                    // blocks per batch
#define FPS_GT (FPS_T * FPS_Q)     // 4096 threads per batch
#define FPS_PPT (FPS_N / FPS_GT)   // 16 points per thread
#define FPS_WAVES (FPS_T / 64)     // 16 waves per block

#define SLOT_U64 8                 // 64B global slot
#define BATCH_U64 (FPS_Q * 2 * SLOT_U64)

#define AG_LOAD(p)    __hip_atomic_load((p), __ATOMIC_RELAXED, __HIP_MEMORY_SCOPE_AGENT)
#define AG_STORE(p,v) __hip_atomic_store((p), (v), __ATOMIC_RELAXED, __HIP_MEMORY_SCOPE_AGENT)

typedef float v2f __attribute__((ext_vector_type(2)));

static __device__ __forceinline__ v2f pk_add(v2f a, v2f b) {
    v2f d; asm("v_pk_add_f32 %0, %1, %2" : "=v"(d) : "v"(a), "v"(b)); return d;
}
static __device__ __forceinline__ v2f pk_mul(v2f a, v2f b) {
    v2f d; asm("v_pk_mul_f32 %0, %1, %2" : "=v"(d) : "v"(a), "v"(b)); return d;
}
static __device__ __forceinline__ v2f pk_fma(v2f a, v2f b, v2f c) {
    v2f d; asm("v_pk_fma_f32 %0, %1, %2, %3" : "=v"(d) : "v"(a), "v"(b), "v"(c)); return d;
}

// residency pin for float2 register pairs (allocation-only, zero instrs)
#define PIN4(a,b,c,d) asm volatile("" : "+v"(a), "+v"(b), "+v"(c), "+v"(d))

__global__ __launch_bounds__(FPS_T, 4)
void fps_kernel(const float* __restrict__ x, float* __restrict__ out,
                unsigned long long* __restrict__ cand) {
    const int bid = blockIdx.x;
    // XCD-affine swizzle (bijective over [0,256))
    const int c = bid & 7;
    const int v = bid >> 3;
    const int q = v & 3;           // block-in-batch
    const int b = (v >> 2) * 8 + c;

    const float* xb = x + (size_t)b * FPS_N * 3;
    float* ob = out + (size_t)b * FPS_M * 3;
    unsigned long long* cb = cand + (size_t)b * BATCH_U64;

    // occupancy fence: 1 block/CU guaranteed (placement determinism)
    __shared__ char s_pad[96 * 1024];
    __shared__ unsigned long long s_entry[FPS_WAVES * 4];
    __shared__ float s_bc[3];

    const int t = threadIdx.x;
    const int wave = t >> 6;
    const int lane = t & 63;
    const int g = q * FPS_T + t;   // 0..4095 within batch

    ((volatile char*)s_pad)[t * 96] = 0;   // keep pad live

    // coords as point-pairs: X j = (x[2j*4096+g], x[(2j+1)*4096+g]) etc.
    v2f X0,X1,X2,X3,X4,X5,X6,X7;
    v2f Y0,Y1,Y2,Y3,Y4,Y5,Y6,Y7;
    v2f Z0,Z1,Z2,Z3,Z4,Z5,Z6,Z7;
    v2f M0,M1,M2,M3,M4,M5,M6,M7;
#define LOADP(j) do { \
        const int i0 = (2*(j)) * FPS_GT + g, i1 = i0 + FPS_GT; \
        X##j = (v2f){xb[3*i0+0], xb[3*i1+0]}; \
        Y##j = (v2f){xb[3*i0+1], xb[3*i1+1]}; \
        Z##j = (v2f){xb[3*i0+2], xb[3*i1+2]}; \
        M##j = (v2f){INFINITY, INFINITY}; } while (0)
    LOADP(0); LOADP(1); LOADP(2); LOADP(3);
    LOADP(4); LOADP(5); LOADP(6); LOADP(7);
#undef LOADP

    float px = xb[0], py = xb[1], pz = xb[2];
    if (q == 0 && t == 0) { ob[0] = px; ob[1] = py; ob[2] = pz; }

    long long budget = 1LL << 22;  // fail-safe for the global poll only

    for (int s = 1; s < FPS_M; ++s) {
        PIN4(X0,X1,X2,X3); PIN4(X4,X5,X6,X7);
        PIN4(Y0,Y1,Y2,Y3); PIN4(Y4,Y5,Y6,Y7);
        PIN4(Z0,Z1,Z2,Z3); PIN4(Z4,Z5,Z6,Z7);

        // negated broadcast point (sub == add of negation, exact)
        const v2f npx = (v2f){-px, -px};
        const v2f npy = (v2f){-py, -py};
        const v2f npz = (v2f){-pz, -pz};

        float best = -INFINITY;
        int bk = 0;
#define STEPP(j) do { \
        const v2f dx = pk_add(X##j, npx); \
        const v2f dy = pk_add(Y##j, npy); \
        const v2f dz = pk_add(Z##j, npz); \
        const v2f sxy = pk_add(pk_mul(dx, dx), pk_mul(dy, dy)); \
        const v2f dd = pk_fma(dz, dz, sxy); \
        const float md0 = fminf(M##j.x, dd.x); \
        const float md1 = fminf(M##j.y, dd.y); \
        M##j.x = md0; M##j.y = md1; \
        if (md0 > best) { best = md0; bk = 2*(j); } \
        if (md1 > best) { best = md1; bk = 2*(j)+1; } } while (0)
        STEPP(0); STEPP(1); STEPP(2); STEPP(3);
        STEPP(4); STEPP(5); STEPP(6); STEPP(7);
#undef STEPP
        int besti = (bk << 12) | g;   // global index = k*4096 + g

        // wave argmax on (val, idx), smallest-index tie-break
#pragma unroll
        for (int m = 32; m >= 1; m >>= 1) {
            const float ov = __shfl_xor(best, m);
            const int   oi = __shfl_xor(besti, m);
            if (ov > best || (ov == best && oi < besti)) { best = ov; besti = oi; }
        }
        // recover winner coords: kw is wave-uniform; owner lane = widx & 63
        const int kw = besti >> 12;
        const int wl = besti & 63;
        float sx, sy, sz;
        switch (kw) {
            case  0: sx = X0.x; sy = Y0.x; sz = Z0.x; break;
            case  1: sx = X0.y; sy = Y0.y; sz = Z0.y; break;
            case  2: sx = X1.x; sy = Y1.x; sz = Z1.x; break;
            case  3: sx = X1.y; sy = Y1.y; sz = Z1.y; break;
            case  4: sx = X2.x; sy = Y2.x; sz = Z2.x; break;
            case  5: sx = X2.y; sy = Y2.y; sz = Z2.y; break;
            case  6: sx = X3.x; sy = Y3.x; sz = Z3.x; break;
            case  7: sx = X3.y; sy = Y3.y; sz = Z3.y; break;
            case  8: sx = X4.x; sy = Y4.x; sz = Z4.x; break;
            case  9: sx = X4.y; sy = Y4.y; sz = Z4.y; break;
            case 10: sx = X5.x; sy = Y5.x; sz = Z5.x; break;
            case 11: sx = X5.y; sy = Y5.y; sz = Z5.y; break;
            case 12: sx = X6.x; sy = Y6.x; sz = Z6.x; break;
            case 13: sx = X6.y; sy = Y6.y; sz = Z6.y; break;
            case 14: sx = X7.x; sy = Y7.x; sz = Z7.x; break;
            default: sx = X7.y; sy = Y7.y; sz = Z7.y; break;
        }
        const float wx = __shfl(sx, wl);
        const float wy = __shfl(sy, wl);
        const float wz = __shfl(sz, wl);

        // wave leaders deposit 4 plain words (low 11 bits zero for seq)
        if (lane < 4) {
            unsigned long long w;
            if (lane == 0)
                w = ((unsigned long long)__float_as_uint(best) << 32) |
                    ((unsigned long long)((~(unsigned)besti) & 0xFFFFu) << 11);
            else if (lane == 1) w = ((unsigned long long)__float_as_uint(wx) << 32);
            else if (lane == 2) w = ((unsigned long long)__float_as_uint(wy) << 32);
            else                w = ((unsigned long long)__float_as_uint(wz) << 32);
            s_entry[wave * 4 + lane] = w;
        }
        __syncthreads();           // barrier 1: entries visible

        const unsigned long long want = (unsigned long long)s;
        const int ring = s & 1;
        float npx2, npy2, npz2;

        if (wave == 0) {
            // lane L holds word (L&3) of wave (L>>2)
            unsigned long long ew = s_entry[lane];
            unsigned long long u = ((lane & 3) == 0) ? ew : 0ull;
#pragma unroll
            for (int m = 4; m <= 32; m <<= 1) {
                const unsigned long long o = __shfl_xor(u, m);
                if (o > u) u = o;
            }
            const unsigned long long bw = __shfl(u, 0);   // block winner word0
            const int widx = (int)((~(unsigned)(bw >> 11)) & 0xFFFFu);
            const int wv = (widx & 1023) >> 6;            // winner wave in block
            if (lane < 4) {
                const unsigned long long pw =
                    ((lane == 0) ? bw : s_entry[wv * 4 + lane]) | want;
                AG_STORE(&cb[(q * 2 + ring) * SLOT_U64 + lane], pw);
            }
            // merged poll: lane -> word (lane&15)&3 of slot (lane&15)>>2
            const int gl = lane & 15;
            unsigned long long pv = 0;
            bool ok = false;
            do {
                if (!ok) {
                    pv = AG_LOAD(&cb[((gl >> 2) * 2 + ring) * SLOT_U64 + (gl & 3)]);
                    ok = ((pv & 0x7FFull) == want);
                }
            } while (!__all(ok) && --budget > 0);
            const unsigned long long m0 = __shfl(pv, 0);
            const unsigned long long m1 = __shfl(pv, 4);
            const unsigned long long m2 = __shfl(pv, 8);
            const unsigned long long m3 = __shfl(pv, 12);
            const unsigned long long w01 = m0 > m1 ? m0 : m1;
            const unsigned long long w23 = m2 > m3 ? m2 : m3;
            const unsigned long long w = w01 > w23 ? w01 : w23;
            const int wb = (w == m0) ? 0 : ((w == m1) ? 1 : ((w == m2) ? 2 : 3));
            npx2 = __uint_as_float((unsigned)(__shfl(pv, wb * 4 + 1) >> 32));
            npy2 = __uint_as_float((unsigned)(__shfl(pv, wb * 4 + 2) >> 32));
            npz2 = __uint_as_float((unsigned)(__shfl(pv, wb * 4 + 3) >> 32));
            if (lane == 0) { s_bc[0] = npx2; s_bc[1] = npy2; s_bc[2] = npz2; }
            if (q == 0 && lane == 0) {
                ob[3 * s + 0] = npx2; ob[3 * s + 1] = npy2; ob[3 * s + 2] = npz2;
            }
        }
        __syncthreads();           // barrier 2: broadcast visible
        if (wave != 0) { npx2 = s_bc[0]; npy2 = s_bc[1]; npz2 = s_bc[2]; }
        px = npx2; py = npy2; pz = npz2;
    }
}

extern "C" void kernel_launch(void* const* d_in, const int* in_sizes, int n_in,
                              void* d_out, int out_size, void* d_ws, size_t ws_size,
                              hipStream_t stream) {
    const float* x = (const float*)d_in[0];
    float* out = (float*)d_out;
    unsigned long long* cand = (unsigned long long*)d_ws;
    (void)in_sizes; (void)n_in; (void)out_size; (void)ws_size;
    hipMemsetAsync(d_ws, 0, FPS_B * BATCH_U64 * sizeof(unsigned long long), stream);
    fps_kernel<<<FPS_B * FPS_Q, FPS_T, 0, stream>>>(x, out, cand);
}